// Round 6
// baseline (441.218 us; speedup 1.0000x reference)
//
#include <hip/hip_runtime.h>
#include <math.h>

// Codebook argmin via split-bf16 MFMA, m97-style DMA double-buffered K-loop.
// cross = xh*ch + xl*ch + xh*cl  (3x v_mfma_f32_32x32x16_bf16).
// Block = 256 thr = 128 pixels x 512 clusters; clusters in 4 sequential
// quarters of 128 (wave = 2mt x 2nt = 64 AGPR). Per iter: A-frags via
// global_load_lds DMA (L2-resident ws), x f32 loads prefetched 1 iter ahead,
// split hi/lo in-reg, ds_write frag-ordered; double-buffered LDS, ONE
// barrier/iter. grid 512 = exactly 2 blocks/CU. fp64 re-check of near-ties.

#define NK   512
#define NC   512
#define NHW  4096
#define PIXB 128
#define MARGIN 0.02f

typedef unsigned short u16;
typedef __attribute__((ext_vector_type(8)))  short  short8;
typedef __attribute__((ext_vector_type(16))) float  f32x16;

__device__ __forceinline__ u16 f2bf_rne(float f) {
    unsigned u = __builtin_bit_cast(unsigned, f);
    u += 0x7FFFu + ((u >> 16) & 1u);
    return (u16)(u >> 16);
}
__device__ __forceinline__ float bf2f(u16 h) {
    unsigned u = ((unsigned)h) << 16;
    return __builtin_bit_cast(float, u);
}

// wcc frag layout: [ch 32][unit 32][lane 64][8 bf16]; unit u = pl*16 + mt
// (pl: 0=hi,1=lo; mt: m-tile of 32 clusters). lane ls: k = mt*32+(ls&31),
// channels c = ch*16 + (ls>>5)*8 + j.  One block per cluster row.
__global__ __launch_bounds__(64) void prep(const float* __restrict__ cc,
                                           u16* __restrict__ wcc,
                                           float* __restrict__ shalf) {
    const int k    = blockIdx.x;
    const int lane = threadIdx.x;
    const float* row = cc + (size_t)k * NC + lane * 8;
    short8 hi, lo;
    float s = 0.f;
    #pragma unroll
    for (int j = 0; j < 8; ++j) {
        float f = row[j];
        s = fmaf(f, f, s);
        u16 h = f2bf_rne(f);
        hi[j] = (short)h;
        lo[j] = (short)f2bf_rne(f - bf2f(h));
    }
    const int ch = lane >> 1;
    const int kh = lane & 1;
    const int mt = k >> 5;
    const int ls = (k & 31) + 32 * kh;
    *(short8*)(wcc + ((size_t)(ch * 32 + mt)      * 64 + ls) * 8) = hi;  // pl=0
    *(short8*)(wcc + ((size_t)(ch * 32 + 16 + mt) * 64 + ls) * 8) = lo;  // pl=1
    #pragma unroll
    for (int off = 32; off > 0; off >>= 1) s += __shfl_down(s, off, 64);
    if (lane == 0) shalf[k] = 0.5f * s;
}

__global__ __launch_bounds__(256) void codebook_mfma(
        const float* __restrict__ x,
        const float* __restrict__ cc,
        const u16* __restrict__ wcc,
        const float* __restrict__ shalf,
        int* __restrict__ out)
{
    // staging buffers: slot s = pl*4 + idx, each slot 64 lanes x 8 u16 = 1KB
    __shared__ __align__(16) u16 As[2][8 * 64 * 8];   // 2 x 8KB
    __shared__ __align__(16) u16 Bs[2][8 * 64 * 8];   // 2 x 8KB
    __shared__ float sh_s[NK];                        // 2KB
    __shared__ float cand_v[4][PIXB + 2];             // ~2KB each
    __shared__ float cand_s[4][PIXB + 2];
    __shared__ int   cand_k[4][PIXB + 2];
    __shared__ float xcol[NC];                        // 2KB
    __shared__ double dvv[256];                       // 2KB
    __shared__ int    dii[256];
    __shared__ int    flagsh[PIXB];
    __shared__ int    bestk_sh[PIXB];

    const int tid = threadIdx.x;
    const int w   = tid >> 6;
    const int l   = tid & 63;
    const int wm  = w & 1;        // m-wave index
    const int wn  = w >> 1;       // n-wave index
    const int rg  = l >> 5;       // C/D row-group

    const int gp0 = blockIdx.x * PIXB;                // 128 | 4096
    const float* xb = x + (size_t)(gp0 >> 12) * (NC * NHW) + (gp0 & (NHW - 1));

    sh_s[tid]       = shalf[tid];
    sh_s[tid + 256] = shalf[tid + 256];

    // x staging role: thread owns (pixel sp, channel-octet coct)
    const int sp    = tid & 127;
    const int coct  = tid >> 7;
    const int bslot_hi = (sp >> 5);          // ng
    const int lslot    = (sp & 31) + 32 * coct;
    const float* xsrc  = xb + sp;

    f32x16 acc[2][2] = {};
    float bestv[2] = {-INFINITY, -INFINITY};
    float secv [2] = {-INFINITY, -INFINITY};
    int   bkv  [2] = {0, 0};

    float nf[8];

    // ---- prologue: stage iteration 0 into buffer 0 ----
    #pragma unroll
    for (int i = 0; i < 2; ++i) {
        const int s = w * 2 + i;
        const int u = (s >> 2) * 16 + (s & 3);       // q=0, ch=0
        __builtin_amdgcn_global_load_lds(
            (const __attribute__((address_space(1))) void*)
                (wcc + ((size_t)u * 64 + l) * 8),
            (__attribute__((address_space(3))) void*)&As[0][s * 512],
            16, 0, 0);
    }
    #pragma unroll
    for (int j = 0; j < 8; ++j)
        nf[j] = xsrc[(size_t)(coct * 8 + j) * NHW];
    {
        unsigned hv[4], lv[4];
        #pragma unroll
        for (int j = 0; j < 4; ++j) {
            float f0 = nf[2 * j], f1 = nf[2 * j + 1];
            unsigned u0 = __builtin_bit_cast(unsigned, f0);
            unsigned u1 = __builtin_bit_cast(unsigned, f1);
            float r0 = f0 - __builtin_bit_cast(float, u0 & 0xFFFF0000u);
            float r1 = f1 - __builtin_bit_cast(float, u1 & 0xFFFF0000u);
            hv[j] = (u0 >> 16) | (u1 & 0xFFFF0000u);
            lv[j] = (__builtin_bit_cast(unsigned, r0) >> 16) |
                    (__builtin_bit_cast(unsigned, r1) & 0xFFFF0000u);
        }
        *(uint4*)&Bs[0][((0 + bslot_hi) * 64 + lslot) * 8] = make_uint4(hv[0], hv[1], hv[2], hv[3]);
        *(uint4*)&Bs[0][((4 + bslot_hi) * 64 + lslot) * 8] = make_uint4(lv[0], lv[1], lv[2], lv[3]);
    }
    __syncthreads();

    // ---- main loop: 4 quarters x 32 chunks = 128 iters, 1 barrier each ----
    #pragma unroll 1
    for (int it = 0; it < 128; ++it) {
        const int cur = it & 1;
        const int nxt = cur ^ 1;

        if (it < 127) {
            const int nq  = (it + 1) >> 5;
            const int nch = (it + 1) & 31;
            #pragma unroll
            for (int i = 0; i < 2; ++i) {
                const int s = w * 2 + i;
                const int u = (s >> 2) * 16 + nq * 4 + (s & 3);
                __builtin_amdgcn_global_load_lds(
                    (const __attribute__((address_space(1))) void*)
                        (wcc + ((size_t)(nch * 32 + u) * 64 + l) * 8),
                    (__attribute__((address_space(3))) void*)&As[nxt][s * 512],
                    16, 0, 0);
            }
            #pragma unroll
            for (int j = 0; j < 8; ++j)
                nf[j] = xsrc[(size_t)(nch * 16 + coct * 8 + j) * NHW];
        }

        // compute from cur buffers
        short8 af[2][2], bf[2][2];     // [pl][j2] / [pl][nt]
        #pragma unroll
        for (int pl = 0; pl < 2; ++pl)
            #pragma unroll
            for (int j2 = 0; j2 < 2; ++j2)
                af[pl][j2] = *(const short8*)&As[cur][((pl * 4 + wm * 2 + j2) * 64 + l) * 8];
        #pragma unroll
        for (int pl = 0; pl < 2; ++pl)
            #pragma unroll
            for (int nt = 0; nt < 2; ++nt)
                bf[pl][nt] = *(const short8*)&Bs[cur][((pl * 4 + wn * 2 + nt) * 64 + l) * 8];

        #pragma unroll
        for (int j2 = 0; j2 < 2; ++j2)
            #pragma unroll
            for (int nt = 0; nt < 2; ++nt)
                acc[j2][nt] = __builtin_amdgcn_mfma_f32_32x32x16_bf16(af[0][j2], bf[0][nt], acc[j2][nt], 0, 0, 0);
        #pragma unroll
        for (int j2 = 0; j2 < 2; ++j2)
            #pragma unroll
            for (int nt = 0; nt < 2; ++nt)
                acc[j2][nt] = __builtin_amdgcn_mfma_f32_32x32x16_bf16(af[1][j2], bf[0][nt], acc[j2][nt], 0, 0, 0);
        #pragma unroll
        for (int j2 = 0; j2 < 2; ++j2)
            #pragma unroll
            for (int nt = 0; nt < 2; ++nt)
                acc[j2][nt] = __builtin_amdgcn_mfma_f32_32x32x16_bf16(af[0][j2], bf[1][nt], acc[j2][nt], 0, 0, 0);

        // convert & write next x tile (loads issued ~full iter ago)
        if (it < 127) {
            unsigned hv[4], lv[4];
            #pragma unroll
            for (int j = 0; j < 4; ++j) {
                float f0 = nf[2 * j], f1 = nf[2 * j + 1];
                unsigned u0 = __builtin_bit_cast(unsigned, f0);
                unsigned u1 = __builtin_bit_cast(unsigned, f1);
                float r0 = f0 - __builtin_bit_cast(float, u0 & 0xFFFF0000u);
                float r1 = f1 - __builtin_bit_cast(float, u1 & 0xFFFF0000u);
                hv[j] = (u0 >> 16) | (u1 & 0xFFFF0000u);
                lv[j] = (__builtin_bit_cast(unsigned, r0) >> 16) |
                        (__builtin_bit_cast(unsigned, r1) & 0xFFFF0000u);
            }
            *(uint4*)&Bs[nxt][((0 + bslot_hi) * 64 + lslot) * 8] = make_uint4(hv[0], hv[1], hv[2], hv[3]);
            *(uint4*)&Bs[nxt][((4 + bslot_hi) * 64 + lslot) * 8] = make_uint4(lv[0], lv[1], lv[2], lv[3]);
        }

        // quarter boundary: fold acc into per-lane top-2, reset acc
        if ((it & 31) == 31) {
            const int q = it >> 5;
            #pragma unroll
            for (int nt = 0; nt < 2; ++nt) {
                #pragma unroll
                for (int j2 = 0; j2 < 2; ++j2) {
                    const int kbase = q * 128 + wm * 64 + j2 * 32 + 4 * rg;
                    #pragma unroll
                    for (int reg = 0; reg < 16; ++reg) {
                        const int k = kbase + (reg & 3) + 8 * (reg >> 2);
                        const float v = acc[j2][nt][reg] - sh_s[k];
                        if (v > bestv[nt]) { secv[nt] = bestv[nt]; bestv[nt] = v; bkv[nt] = k; }
                        else if (v > secv[nt]) secv[nt] = v;
                    }
                    acc[j2][nt] = (f32x16)(0.f);
                }
            }
        }
        __syncthreads();
    }

    // ---- combine across lanes: 4 slots per pixel (wm x rg) ----
    #pragma unroll
    for (int nt = 0; nt < 2; ++nt) {
        const int p    = wn * 64 + nt * 32 + (l & 31);
        const int slot = wm * 2 + rg;
        cand_v[slot][p] = bestv[nt];
        cand_s[slot][p] = secv[nt];
        cand_k[slot][p] = bkv[nt];
    }
    __syncthreads();

    if (tid < PIXB) {
        float best = -INFINITY, sec = -INFINITY;
        int bk = 1 << 30;
        #pragma unroll
        for (int s = 0; s < 4; ++s) {
            float v  = cand_v[s][tid];
            float v2 = cand_s[s][tid];
            int  kk  = cand_k[s][tid];
            if (v > best || (v == best && kk < bk)) {
                sec = fmaxf(sec, best);
                best = v; bk = kk;
            } else sec = fmaxf(sec, v);
            sec = fmaxf(sec, v2);
        }
        bestk_sh[tid] = bk;
        flagsh[tid] = (best - sec < MARGIN) ? 1 : 0;
    }
    __syncthreads();

    // fp64 full re-check for near-tie pixels (rare)
    for (int pix = 0; pix < PIXB; ++pix) {
        if (!flagsh[pix]) continue;              // uniform (LDS) branch
        for (int c = tid; c < NC; c += 256)
            xcol[c] = xb[(size_t)c * NHW + pix];
        __syncthreads();
        double bd = 1e300;
        int bkk = 1 << 30;
        #pragma unroll
        for (int r = 0; r < 2; ++r) {
            const int k = tid + r * 256;
            const float4* crow = (const float4*)(cc + (size_t)k * NC);
            const float4* xc4  = (const float4*)xcol;
            double d = 0.0;
            for (int c4 = 0; c4 < NC / 4; ++c4) {
                float4 cv = crow[c4], xv = xc4[c4];
                double d0 = (double)xv.x - (double)cv.x;
                double d1 = (double)xv.y - (double)cv.y;
                double d2 = (double)xv.z - (double)cv.z;
                double d3 = (double)xv.w - (double)cv.w;
                d = fma(d0, d0, d); d = fma(d1, d1, d);
                d = fma(d2, d2, d); d = fma(d3, d3, d);
            }
            if (d < bd || (d == bd && k < bkk)) { bd = d; bkk = k; }
        }
        dvv[tid] = bd; dii[tid] = bkk;
        __syncthreads();
        for (int srd = 128; srd > 0; srd >>= 1) {
            if (tid < srd) {
                double ov = dvv[tid + srd]; int oi = dii[tid + srd];
                if (ov < dvv[tid] || (ov == dvv[tid] && oi < dii[tid])) {
                    dvv[tid] = ov; dii[tid] = oi;
                }
            }
            __syncthreads();
        }
        if (tid == 0) bestk_sh[pix] = dii[0];
        __syncthreads();
    }

    if (tid < PIXB) out[gp0 + tid] = bestk_sh[tid];
}

extern "C" void kernel_launch(void* const* d_in, const int* in_sizes, int n_in,
                              void* d_out, int out_size, void* d_ws, size_t ws_size,
                              hipStream_t stream) {
    const float* x  = (const float*)d_in[0];   // (16, 512, 64, 64) f32
    const float* cc = (const float*)d_in[1];   // (1, 512, 512, 1, 1) f32
    int* out = (int*)d_out;                    // (16, 1, 64, 64) int32

    float* shalf = (float*)d_ws;               // 512 floats
    u16*   wcc   = (u16*)(shalf + NK);         // 1MB frag-ordered hi/lo bf16

    prep<<<NK, 64, 0, stream>>>(cc, wcc, shalf);
    codebook_mfma<<<(16 * NHW) / PIXB, 256, 0, stream>>>(x, cc, wcc, shalf, out);
}